// Round 14
// baseline (11081.028 us; speedup 1.0000x reference)
//
#include <hip/hip_runtime.h>
#include <hip/hip_bf16.h>
#include <hip/hip_cooperative_groups.h>

namespace cg = cooperative_groups;

#define SEQ 512
#define BATCH 128
#define INP 512
#define HID 1024
#define CLASSES 1000
#define KTOT 1536
#define NKT 48
#define NKX 16
#define NKH 32

#define NBLK 256
#define NTHR 512
#define HSZ (16 * 1024)        // ushorts per fast parity buffer (16 rows x 1024)

typedef float f32x4 __attribute__((ext_vector_type(4)));
typedef short bf16x8 __attribute__((ext_vector_type(8)));
typedef int   v4i   __attribute__((ext_vector_type(4)));

__device__ __forceinline__ short f2bf16s(float f) {
    __hip_bfloat16 h = __float2bfloat16(f);
    return __builtin_bit_cast(short, h);
}
__device__ __forceinline__ float sigmoidf_(float x) {
    return 1.0f / (1.0f + __expf(-x));
}
__device__ __forceinline__ float tanhf_(float x) {
    x = fminf(fmaxf(x, -15.0f), 15.0f);
    float e = __expf(2.0f * x);
    return (e - 1.0f) / (e + 1.0f);
}

// ================= K1: fp32 -> bf16 convert (x, W_ih) =====================
#define XCH (SEQ * BATCH * INP / 8)
#define WCH (4 * HID * INP / 8)
__global__ __launch_bounds__(256)
void convert_bf16(const float* __restrict__ x, const float* __restrict__ W_ih,
                  unsigned short* __restrict__ xbf, unsigned short* __restrict__ Wbf) {
    const size_t total = XCH + WCH;
    for (size_t c = (size_t)blockIdx.x * blockDim.x + threadIdx.x; c < total;
         c += (size_t)gridDim.x * blockDim.x) {
        const float* src; unsigned short* dst;
        if (c < XCH) { src = x + c * 8;            dst = xbf + c * 8; }
        else         { src = W_ih + (c - XCH) * 8; dst = Wbf + (c - XCH) * 8; }
        const float4 a = *(const float4*)src;
        const float4 b = *(const float4*)(src + 4);
        bf16x8 v;
        v[0] = f2bf16s(a.x); v[1] = f2bf16s(a.y);
        v[2] = f2bf16s(a.z); v[3] = f2bf16s(a.w);
        v[4] = f2bf16s(b.x); v[5] = f2bf16s(b.y);
        v[6] = f2bf16s(b.z); v[7] = f2bf16s(b.w);
        *(bf16x8*)dst = v;
    }
}

// ================= K2: xproj, universal layout xpp[t][n][m] (fp32) ========
// n = gate row (0..4095), m = batch (0..127). Every consumer lane reads one
// contiguous float4 (4 consecutive m for fixed n).
__global__ __launch_bounds__(256)
void xproj_gemm(const unsigned short* __restrict__ xbf,
                const unsigned short* __restrict__ Wbf,
                float* __restrict__ xpp) {
    const int tid = threadIdx.x;
    const int w = tid >> 6;
    const int lane = tid & 63;
    const int ln15 = lane & 15;
    const int lgrp = lane >> 4;
    const int k8 = lgrp * 8;
    const int bx = blockIdx.x;                    // timestep t
    const int m0 = bx * 128 + w * 32 + ln15;
    const int n0 = blockIdx.y * 128 + ln15;

    f32x4 acc[2][8];
    #pragma unroll
    for (int i = 0; i < 2; i++)
        #pragma unroll
        for (int j = 0; j < 8; j++) acc[i][j] = (f32x4){0.f, 0.f, 0.f, 0.f};

    #pragma unroll 4
    for (int kt = 0; kt < INP / 32; kt++) {
        const int k = kt * 32 + k8;
        bf16x8 a0 = *(const bf16x8*)(xbf + (size_t)m0 * INP + k);
        bf16x8 a1 = *(const bf16x8*)(xbf + (size_t)(m0 + 16) * INP + k);
        #pragma unroll
        for (int nt = 0; nt < 8; nt++) {
            bf16x8 b = *(const bf16x8*)(Wbf + (size_t)(n0 + nt * 16) * INP + k);
            acc[0][nt] = __builtin_amdgcn_mfma_f32_16x16x32_bf16(a0, b, acc[0][nt], 0, 0, 0);
            acc[1][nt] = __builtin_amdgcn_mfma_f32_16x16x32_bf16(a1, b, acc[1][nt], 0, 0, 0);
        }
    }
    // C/D: m_in_tile = lgrp*4 + r, n = ln15 -> float4 along m.
    #pragma unroll
    for (int nt = 0; nt < 8; nt++) {
        const int n = blockIdx.y * 128 + nt * 16 + ln15;
        #pragma unroll
        for (int mi = 0; mi < 2; mi++) {
            const int m = w * 32 + mi * 16 + lgrp * 4;   // within-t batch base
            size_t base = ((size_t)bx * 4096 + n) * 128 + m;
            *(float4*)(xpp + base) = *(float4*)&acc[mi][nt];
        }
    }
}

// ================= K3: hybrid recurrent kernel ============================
// ctrl (d_out, memset 0 each call):
//  [0..7]  per-XCD claim counters   [9] handshake votes
//  [16..271] handshake words        [512+g*64+e] fast flags
//  [1024+bid] slow flags
__device__ __forceinline__ void slow_wait(const unsigned* sflags, int lane,
                                          unsigned want) {
    const unsigned* p0 = &sflags[lane];
    const unsigned* p1 = &sflags[64 + lane];
    for (;;) {
        unsigned f0 = __hip_atomic_load(p0, __ATOMIC_RELAXED,
                                        __HIP_MEMORY_SCOPE_AGENT);
        unsigned f1 = __hip_atomic_load(p1, __ATOMIC_RELAXED,
                                        __HIP_MEMORY_SCOPE_AGENT);
        if (__all((f0 >= want) && (f1 >= want))) break;
        __builtin_amdgcn_s_sleep(1);
    }
    __builtin_amdgcn_fence(__ATOMIC_ACQUIRE, "agent");
}

__global__ __launch_bounds__(NTHR)
void lstm_hybrid(const float* __restrict__ W_hh,
                 const float* __restrict__ b_ih,
                 const float* __restrict__ b_hh,
                 const float* __restrict__ W_ih,
                 const float* __restrict__ W_fc,
                 const float* __restrict__ b_fc,
                 float* __restrict__ out,
                 const float* __restrict__ xpp,
                 const unsigned short* __restrict__ xbf,
                 unsigned short* __restrict__ hbuf,   // == h0 region (overlap)
                 unsigned short* __restrict__ h0,
                 unsigned short* __restrict__ h1,
                 unsigned* __restrict__ ctrl,
                 int use_xp)
{
    __shared__ short W_sw[2 * NKT * 64 * 8];   // 98304 B (slow path)
    __shared__ short hstage[HSZ];              // 32768 B (fast path)
    __shared__ float gwf[4][32][17];           //  8704 B (fast)
    __shared__ float gws[8][16][33];           // 16896 B (slow)
    __shared__ int s_role, s_fast;

    const int tid = threadIdx.x;
    const int bid = blockIdx.x;

    // ---- phase 1: claim a slot on own XCD ----
    if (tid == 0) {
        int xcc;
        asm volatile("s_getreg_b32 %0, hwreg(HW_REG_XCC_ID)" : "=s"(xcc));
        xcc &= 7;
        unsigned slot = __hip_atomic_fetch_add(&ctrl[xcc], 1u, __ATOMIC_RELAXED,
                                               __HIP_MEMORY_SCOPE_AGENT);
        s_role = (slot < 32u) ? (xcc * 32 + (int)slot) : -1;
    }
    {   // zero h0 (slow path initial h): 65536 dwords over 131072 threads
        const unsigned gt = (unsigned)bid * NTHR + tid;
        if (gt < (unsigned)(BATCH * HID / 2)) ((unsigned*)h0)[gt] = 0u;
    }
    __syncthreads();
    const int role = s_role;

    // ---- phase 2: handshake — prove same-L2 visibility with the EXACT
    //      store/load mechanism the fast loop will use (bounded) ----
    if (tid == 0 && role >= 0) {
        volatile unsigned* hs = ctrl + 16;
        hs[role] = 0x5A5A0000u | (unsigned)role;          // plain store -> local L2
        asm volatile("s_waitcnt vmcnt(0)" ::: "memory");
        const unsigned want = 0x5A5A0000u | (unsigned)(role ^ 1);
        const unsigned* pp = (const unsigned*)(ctrl + 16 + (role ^ 1));
        int pass = 0;
        for (int it = 0; it < 60000; ++it) {
            unsigned v;
            asm volatile("global_load_dword %0, %1, off sc0\n\t"
                         "s_waitcnt vmcnt(0)"
                         : "=v"(v) : "v"(pp) : "memory");
            if (v == want) { pass = 1; break; }
        }
        if (pass)
            __hip_atomic_fetch_add(&ctrl[9], 1u, __ATOMIC_RELAXED,
                                   __HIP_MEMORY_SCOPE_AGENT);
    }
    __syncthreads();
    cg::this_grid().sync();     // claims/votes/h0 final and visible

    if (tid == 0) {
        unsigned v9 = __hip_atomic_load(&ctrl[9], __ATOMIC_RELAXED,
                                        __HIP_MEMORY_SCOPE_AGENT);
        s_fast = (v9 == (unsigned)NBLK && use_xp) ? 1 : 0;
    }
    __syncthreads();
    const bool fast = (s_fast != 0);

    const int wave = tid >> 6;
    const int lane = tid & 63;
    const int ln15 = lane & 15;
    const int lgrp = lane >> 4;

    if (fast) {
        // =================== XCD-local fast path ===================
        const int g = role >> 5;               // batch group / XCD
        const int e = role & 31;               // h-col slice (32 cols)
        const int gate = wave >> 1;
        const int half = wave & 1;

        // W_hh slice -> VGPRs, fragment order (128 VGPR/lane)
        bf16x8 Wreg[32];
        {
            const int nrow = gate * HID + e * 32 + half * 16 + ln15;
            const float* wbase = W_hh + (size_t)nrow * HID + lgrp * 8;
            #pragma unroll
            for (int kt = 0; kt < 32; kt++) {
                const float4 wa = *(const float4*)(wbase + kt * 32);
                const float4 wb = *(const float4*)(wbase + kt * 32 + 4);
                bf16x8 v;
                v[0] = f2bf16s(wa.x); v[1] = f2bf16s(wa.y);
                v[2] = f2bf16s(wa.z); v[3] = f2bf16s(wa.w);
                v[4] = f2bf16s(wb.x); v[5] = f2bf16s(wb.y);
                v[6] = f2bf16s(wb.z); v[7] = f2bf16s(wb.w);
                Wreg[kt] = v;
            }
        }
        const int cm = tid >> 4;               // 0..31 -> m row (only tid<256)
        const int cp = (tid & 15) * 2;
        float c_r[2] = {0.f, 0.f};
        float bias_r[2][4];
        if (tid < 256) {
            #pragma unroll
            for (int jj = 0; jj < 2; jj++)
                #pragma unroll
                for (int g4 = 0; g4 < 4; g4++) {
                    const int r = g4 * HID + e * 32 + cp + jj;
                    bias_r[jj][g4] = b_ih[r] + b_hh[r];
                }
        }
        unsigned short* const hgrp = hbuf + (size_t)g * 2 * HSZ;
        unsigned* const flagF = ctrl + 512 + g * 64;

        const int srow = tid & 15;
        const int sq   = (tid >> 4) * 4;
        const int sx   = (srow & 7) << 4;
        char* const hsb = (char*)hstage;
        const int rx = (ln15 & 7) << 4;
        const int nF = gate * HID + e * 32 + half * 16 + ln15;
        const int mF = g * 16 + lgrp * 4;

        for (int t = 0; t < SEQ; t++) {
            const float4 xv = *(const float4*)(xpp +
                ((size_t)t * 4096 + nF) * 128 + mF);

            f32x4 acc;
            if (t > 0) {
                // wait for group's 32 producers (L2-local; mechanism proven)
                {
                    const unsigned* fp = flagF + (lane & 31);
                    for (;;) {
                        unsigned f;
                        asm volatile("global_load_dword %0, %1, off sc0\n\t"
                                     "s_waitcnt vmcnt(0)"
                                     : "=v"(f) : "v"(fp) : "memory");
                        if (__all(f >= (unsigned)t)) break;
                    }
                }
                // stage h_t (32KB) into swizzled LDS via sc0 loads
                const unsigned short* hb = hgrp + (size_t)(t & 1) * HSZ
                                         + (size_t)srow * HID + sq * 8;
                v4i a0, a1, a2, a3;
                {
                    const v4i* p0 = (const v4i*)hb;
                    asm volatile(
                        "global_load_dwordx4 %0, %4, off sc0\n\t"
                        "global_load_dwordx4 %1, %5, off sc0\n\t"
                        "global_load_dwordx4 %2, %6, off sc0\n\t"
                        "global_load_dwordx4 %3, %7, off sc0\n\t"
                        "s_waitcnt vmcnt(0)"
                        : "=&v"(a0), "=&v"(a1), "=&v"(a2), "=&v"(a3)
                        : "v"(p0), "v"(p0 + 1), "v"(p0 + 2), "v"(p0 + 3)
                        : "memory");
                }
                {
                    const int dbase = srow * 2048;
                    *(v4i*)(hsb + dbase + (((sq + 0) * 16) ^ sx)) = a0;
                    *(v4i*)(hsb + dbase + (((sq + 1) * 16) ^ sx)) = a1;
                    *(v4i*)(hsb + dbase + (((sq + 2) * 16) ^ sx)) = a2;
                    *(v4i*)(hsb + dbase + (((sq + 3) * 16) ^ sx)) = a3;
                }
                __syncthreads();

                acc = (f32x4){xv.x, xv.y, xv.z, xv.w};
                const int rbase = ln15 * 2048;
                #pragma unroll
                for (int kt = 0; kt < 32; kt++) {
                    bf16x8 a = *(const bf16x8*)(hsb + rbase +
                                                ((kt * 64 + lgrp * 16) ^ rx));
                    acc = __builtin_amdgcn_mfma_f32_16x16x32_bf16(a, Wreg[kt], acc, 0, 0, 0);
                }
            } else {
                acc = (f32x4){xv.x, xv.y, xv.z, xv.w};    // h0 = 0
            }

            {   // transpose (C/D: m = lgrp*4+r, col = half*16+ln15)
                const int col = half * 16 + ln15;
                #pragma unroll
                for (int r = 0; r < 4; r++)
                    gwf[gate][col][lgrp * 4 + r] = acc[r];
            }
            __syncthreads();

            if (tid < 256) {
                unsigned pack = 0;
                #pragma unroll
                for (int jj = 0; jj < 2; jj++) {
                    const int col = cp + jj;
                    float ig = gwf[0][col][cm] + bias_r[jj][0];
                    float fg = gwf[1][col][cm] + bias_r[jj][1];
                    float gg = gwf[2][col][cm] + bias_r[jj][2];
                    float og = gwf[3][col][cm] + bias_r[jj][3];
                    ig = sigmoidf_(ig); fg = sigmoidf_(fg);
                    gg = tanhf_(gg);    og = sigmoidf_(og);
                    float cc = fg * c_r[jj] + ig * gg;
                    c_r[jj] = cc;
                    float h = og * tanhf_(cc);
                    pack |= ((unsigned)(unsigned short)f2bf16s(h)) << (16 * jj);
                }
                *(unsigned*)(hgrp + (size_t)((t + 1) & 1) * HSZ
                             + (size_t)cm * HID + e * 32 + cp) = pack;
            }
            asm volatile("s_waitcnt vmcnt(0)" ::: "memory");   // acked at L2
            __syncthreads();
            if (tid == 0) {
                *(volatile unsigned*)(flagF + e) = (unsigned)(t + 1);
            }
            __syncthreads();
        }
    } else if (bid < 128) {
        // =================== proven R6 slow path ===================
        const int j0 = bid * 8;
        for (int f = tid; f < 2 * NKT * 64; f += NTHR) {
            const int ln = f & 63;
            const int kt = (f >> 6) % NKT;
            const int nt = f / (NKT * 64);
            const int n = nt * 16 + (ln & 15);
            const int r = (n >> 3) * HID + j0 + (n & 7);
            const int kbase = kt * 32 + (ln >> 4) * 8;
            short tmp[8];
            #pragma unroll
            for (int j = 0; j < 8; j++) {
                const int k = kbase + j;
                float w = (k < INP) ? W_ih[(size_t)r * INP + k]
                                    : W_hh[(size_t)r * HID + (k - INP)];
                tmp[j] = f2bf16s(w);
            }
            *(bf16x8*)&W_sw[(size_t)f * 8] = *(bf16x8*)tmp;
        }
        const int arow = wave * 16 + ln15;
        const int k8 = lgrp * 8;
        const int crow = lane >> 2;
        const int cp   = (lane & 3) * 2;
        const int bg   = wave * 16 + crow;
        float c_r[2] = {0.f, 0.f};
        float bias_r[2][4];
        #pragma unroll
        for (int jj = 0; jj < 2; jj++)
            #pragma unroll
            for (int g4 = 0; g4 < 4; g4++) {
                const int r = g4 * HID + j0 + cp + jj;
                bias_r[jj][g4] = b_ih[r] + b_hh[r];
            }
        const int nA = (ln15 >> 3) * HID + j0 + (ln15 & 7);
        const int nB = nA + 2 * HID;
        const int mA = wave * 16 + lgrp * 4;
        unsigned* const sflags = ctrl + 1024;
        const bf16x8* Wl = (const bf16x8*)W_sw + lane;
        __syncthreads();

        for (int t = 0; t < SEQ; t++) {
            const unsigned short* hp = (t & 1) ? h1 : h0;
            unsigned short* hcur     = (t & 1) ? h0 : h1;

            f32x4 acc00, acc01;
            if (use_xp) {
                const float4 xv0 = *(const float4*)(xpp + ((size_t)t * 4096 + nA) * 128 + mA);
                const float4 xv1 = *(const float4*)(xpp + ((size_t)t * 4096 + nB) * 128 + mA);
                acc00 = (f32x4){xv0.x, xv0.y, xv0.z, xv0.w};
                acc01 = (f32x4){xv1.x, xv1.y, xv1.z, xv1.w};
            } else {
                acc00 = (f32x4){0.f,0.f,0.f,0.f};
                acc01 = (f32x4){0.f,0.f,0.f,0.f};
                const unsigned short* xr =
                    xbf + (size_t)t * (BATCH * INP) + (size_t)arow * INP + k8;
                #pragma unroll
                for (int kt = 0; kt < NKX; kt++) {
                    bf16x8 a  = *(const bf16x8*)(xr + kt * 32);
                    acc00 = __builtin_amdgcn_mfma_f32_16x16x32_bf16(a, Wl[kt * 64], acc00, 0, 0, 0);
                    acc01 = __builtin_amdgcn_mfma_f32_16x16x32_bf16(a, Wl[(NKT + kt) * 64], acc01, 0, 0, 0);
                }
            }

            if (tid < 64) slow_wait(sflags, lane, (unsigned)t);
            __syncthreads();

            {
                const unsigned short* hr = hp + (size_t)arow * HID + k8;
                #pragma unroll
                for (int kt = 0; kt < NKH; kt++) {
                    bf16x8 a  = *(const bf16x8*)(hr + kt * 32);
                    acc00 = __builtin_amdgcn_mfma_f32_16x16x32_bf16(a, Wl[(NKX + kt) * 64], acc00, 0, 0, 0);
                    acc01 = __builtin_amdgcn_mfma_f32_16x16x32_bf16(a, Wl[(NKT + NKX + kt) * 64], acc01, 0, 0, 0);
                }
            }
            {
                const int r0 = lgrp * 4;
                #pragma unroll
                for (int r = 0; r < 4; r++) {
                    gws[wave][r0 + r][ln15]      = acc00[r];
                    gws[wave][r0 + r][16 + ln15] = acc01[r];
                }
            }
            {
                unsigned pack = 0;
                #pragma unroll
                for (int jj = 0; jj < 2; jj++) {
                    const int dj = cp + jj;
                    float ig = gws[wave][crow][dj]      + bias_r[jj][0];
                    float fg = gws[wave][crow][8 + dj]  + bias_r[jj][1];
                    float gg = gws[wave][crow][16 + dj] + bias_r[jj][2];
                    float og = gws[wave][crow][24 + dj] + bias_r[jj][3];
                    ig = sigmoidf_(ig); fg = sigmoidf_(fg);
                    gg = tanhf_(gg);    og = sigmoidf_(og);
                    float cc = fg * c_r[jj] + ig * gg;
                    c_r[jj] = cc;
                    float h = og * tanhf_(cc);
                    pack |= ((unsigned)(unsigned short)f2bf16s(h)) << (16 * jj);
                }
                __hip_atomic_store((unsigned*)(hcur + (size_t)bg * HID + j0 + cp),
                                   pack, __ATOMIC_RELAXED, __HIP_MEMORY_SCOPE_AGENT);
            }
            asm volatile("s_waitcnt vmcnt(0)" ::: "memory");
            __syncthreads();
            if (tid == 0)
                __hip_atomic_store(&sflags[bid], (unsigned)(t + 1),
                                   __ATOMIC_RELAXED, __HIP_MEMORY_SCOPE_AGENT);
        }
    }
    // slow-mode blocks 128..255 fall through directly

    cg::this_grid().sync();    // release (L2 writeback) + acquire for FC

    // ---- FC epilogue (all 256 blocks) ----
    for (unsigned idx = (unsigned)bid * NTHR + tid; idx < BATCH * CLASSES;
         idx += (unsigned)NBLK * NTHR) {
        const int b   = idx / CLASSES;
        const int cls = idx % CLASSES;
        const unsigned short* hrow = fast
            ? hbuf + (size_t)(b >> 4) * 2 * HSZ + (size_t)(b & 15) * HID
            : h0 + (size_t)b * HID;                 // SEQ even -> h0
        const float* wrow = W_fc + (size_t)cls * HID;
        float acc = 0.f;
        #pragma unroll 4
        for (int k = 0; k < HID; k += 8) {
            bf16x8 hv = *(const bf16x8*)(hrow + k);
            float4 w0 = *(const float4*)(wrow + k);
            float4 w1 = *(const float4*)(wrow + k + 4);
            union { unsigned u; float f; } ee;
            float s = 0.f;
            ee.u = ((unsigned)(unsigned short)hv[0]) << 16; s += ee.f * w0.x;
            ee.u = ((unsigned)(unsigned short)hv[1]) << 16; s += ee.f * w0.y;
            ee.u = ((unsigned)(unsigned short)hv[2]) << 16; s += ee.f * w0.z;
            ee.u = ((unsigned)(unsigned short)hv[3]) << 16; s += ee.f * w0.w;
            ee.u = ((unsigned)(unsigned short)hv[4]) << 16; s += ee.f * w1.x;
            ee.u = ((unsigned)(unsigned short)hv[5]) << 16; s += ee.f * w1.y;
            ee.u = ((unsigned)(unsigned short)hv[6]) << 16; s += ee.f * w1.z;
            ee.u = ((unsigned)(unsigned short)hv[7]) << 16; s += ee.f * w1.w;
            acc += s;
        }
        out[idx] = acc + b_fc[cls];
    }
}

extern "C" void kernel_launch(void* const* d_in, const int* in_sizes, int n_in,
                              void* d_out, int out_size, void* d_ws, size_t ws_size,
                              hipStream_t stream) {
    const float* x    = (const float*)d_in[0];
    const float* W_ih = (const float*)d_in[1];
    const float* W_hh = (const float*)d_in[2];
    const float* b_ih = (const float*)d_in[3];
    const float* b_hh = (const float*)d_in[4];
    const float* W_fc = (const float*)d_in[5];
    const float* b_fc = (const float*)d_in[6];
    float* out = (float*)d_out;

    // ws: [hbuf | h0/h1 overlap 512KB] | xbf 64MB | Wbf 4MB | xpp 1GB
    // (fast uses hbuf, slow uses h0/h1 — mutually exclusive, so they alias)
    const size_t OFF_XBF = 524288;
    const size_t XBF_B   = (size_t)SEQ * BATCH * INP * 2;
    const size_t OFF_WBF = OFF_XBF + XBF_B;
    const size_t WBF_B   = (size_t)4 * HID * INP * 2;
    const size_t OFF_XPP = OFF_WBF + WBF_B;
    const size_t XPP_B   = (size_t)SEQ * BATCH * 4 * HID * 4;   // 1 GB

    unsigned short* hbuf = (unsigned short*)d_ws;
    unsigned short* h0   = (unsigned short*)d_ws;
    unsigned short* h1   = h0 + (size_t)BATCH * HID;
    unsigned short* xbf  = (unsigned short*)((char*)d_ws + OFF_XBF);
    unsigned short* Wbf  = (unsigned short*)((char*)d_ws + OFF_WBF);
    float*          xpp  = (float*)((char*)d_ws + OFF_XPP);

    int use_xp = (ws_size >= OFF_XPP + XPP_B) ? 1 : 0;

    unsigned* ctrl = (unsigned*)d_out;       // overwritten by FC at the end
    hipMemsetAsync(ctrl, 0, 8192, stream);   // counters/votes/handshake/flags

    convert_bf16<<<dim3(2048), dim3(256), 0, stream>>>(x, W_ih, xbf, Wbf);
    if (use_xp) {
        xproj_gemm<<<dim3(512, 32), dim3(256), 0, stream>>>(xbf, Wbf, xpp);
    }

    void* args[] = {&W_hh, &b_ih, &b_hh, &W_ih, &W_fc, &b_fc, &out,
                    &xpp, &xbf, &hbuf, &h0, &h1, &ctrl, &use_xp};
    hipLaunchCooperativeKernel((void*)lstm_hybrid, dim3(NBLK), dim3(NTHR),
                               args, 0, stream);
}